// Round 8
// baseline (7036.818 us; speedup 1.0000x reference)
//
#include <hip/hip_runtime.h>
#include <math.h>

// LSTM encode, round 8: 8 timesteps per cooperative launch (64 nodes).
// Cross-block h exchange via device-coherent (relaxed AGENT atomic) u32
// loads/stores -- NO __threadfence, NO cache invalidation in the loop.
// Per-step sync: vmcnt(0) drain + one relaxed fetch_add per block; one
// polling wave per block on a monotonic flag (separate cacheline).
// Bhi in LDS (staged once per launch), Blo in registers, c in registers
// across internal steps, bf16x3 split MFMA as rounds 2-7.

#define HIDDEN 512
#define TSTEPS 512
#define BATCH 256
#define FEATD 128
#define ACTD 32
#define DIMD 160
#define GATES 2048
#define NKT 21
#define NGROUPS 32
#define NFRAGS (NGROUPS * NKT * 4)   // 2688

#define NSTEP 8               // timesteps per launch
#define NWAVES 8
#define SB 66                 // zbuf stride per b-row (f32)
#define SW (32 * SB)

typedef short bf16x8 __attribute__((ext_vector_type(8)));
typedef float f32x4 __attribute__((ext_vector_type(4)));

__device__ __forceinline__ unsigned short f2bf(float v) {
    union { float f; unsigned u; } c; c.f = v;
    unsigned r = c.u + 0x7fffu + ((c.u >> 16) & 1u);   // RNE
    return (unsigned short)(r >> 16);
}
__device__ __forceinline__ float bf2f(unsigned short s) {
    union { unsigned u; float f; } c; c.u = ((unsigned)s) << 16; return c.f;
}
__device__ __forceinline__ float fast_sigmoid(float x) {
    return 1.0f / (1.0f + __expf(-x));
}
__device__ __forceinline__ float fast_tanh(float x) {
    return 1.0f - 2.0f / (__expf(2.0f * x) + 1.0f);
}

// ---- pack [W;U] (672 x 2048 fp32) into B-fragment-ordered hi/lo bf16 -------
__global__ __launch_bounds__(256)
void pack_weights(const float* __restrict__ W, const float* __restrict__ U,
                  unsigned short* __restrict__ Bhi, unsigned short* __restrict__ Blo)
{
    const int idx = blockIdx.x * 256 + threadIdx.x;
    if (idx >= NFRAGS * 64) return;
    const int lane = idx & 63;
    const int f = idx >> 6;
    const int tc = f & 3;
    const int kt = (f >> 2) % NKT;
    const int ng = (f >> 2) / NKT;
    const int col = tc * HIDDEN + ng * 16 + (lane & 15);
    const int kbase = kt * 32 + (lane >> 4) * 8;
    #pragma unroll
    for (int j = 0; j < 8; ++j) {
        const int k = kbase + j;
        const float v = (k < DIMD) ? W[(size_t)k * GATES + col]
                                   : U[(size_t)(k - DIMD) * GATES + col];
        const unsigned short hi = f2bf(v);
        Bhi[(size_t)idx * 8 + j] = hi;
        Blo[(size_t)idx * 8 + j] = f2bf(v - bf2f(hi));
    }
}

// coherent (device-scope) u32 load/store of packed h (hi | lo<<16)
__device__ __forceinline__ unsigned h_load(const unsigned* p) {
    return __hip_atomic_load(p, __ATOMIC_RELAXED, __HIP_MEMORY_SCOPE_AGENT);
}
__device__ __forceinline__ void h_store(unsigned* p, unsigned v) {
    __hip_atomic_store(p, v, __ATOMIC_RELAXED, __HIP_MEMORY_SCOPE_AGENT);
}

// load 8 packed cells -> hi/lo bf16x8 fragments
__device__ __forceinline__ void h_frag(const unsigned* base, bf16x8& hi, bf16x8& lo) {
    unsigned v[8];
    #pragma unroll
    for (int j = 0; j < 8; ++j) v[j] = h_load(base + j);
    union { bf16x8 s; unsigned u[4]; } PH, PL;
    #pragma unroll
    for (int j = 0; j < 4; ++j) {
        const unsigned a = v[2 * j], b = v[2 * j + 1];
        PH.u[j] = (a & 0xffffu) | (b << 16);
        PL.u[j] = (a >> 16) | (b & 0xffff0000u);
    }
    hi = PH.s; lo = PL.s;
}

__global__ __launch_bounds__(512, 1)
void lstm_multi(const float* __restrict__ feat, const float* __restrict__ act,
                const unsigned short* __restrict__ Bhi,
                const unsigned short* __restrict__ Blo,
                const float* __restrict__ bias,
                unsigned* __restrict__ hp0, unsigned* __restrict__ hp1,
                float* __restrict__ c_st, float* __restrict__ out,
                int* __restrict__ bar, int base)
{
    __shared__ unsigned short lds_bhi[84 * 512];   // 86016 B
    __shared__ float zbuf[NWAVES * SW];            // 67584 B (total 153600)

    const int tid = threadIdx.x;
    const int lane = tid & 63;
    const int w = tid >> 6;
    const int ng = blockIdx.x;
    const int mb = blockIdx.y;
    const int m0 = mb * 32;
    const int u0 = ng * 16;
    const int kg = lane >> 4;
    const int nn = lane & 15;

    // ---- stage my Bhi slab into LDS (amortized over NSTEP steps) -----------
    {
        const uint4* src = (const uint4*)(Bhi + (size_t)ng * 84 * 512);
        uint4* dst = (uint4*)lds_bhi;
        for (int i = tid; i < 84 * 512 / 8; i += 512) dst[i] = src[i];
    }

    // ---- per-wave K assignment; Blo slices in registers --------------------
    const int ktA = (w < 5) ? w : 5;    // x tile for w<5 (dummy=5 otherwise)
    const int ktB = 5 + 2 * w;          // h tiles {5,6}..{19,20}
    const int ktC = 6 + 2 * w;
    bf16x8 bloA[4], bloB[4], bloC[4];
    {
        const unsigned short* blbase = Blo + (size_t)ng * NKT * 2048 + (size_t)lane * 8;
        #pragma unroll
        for (int tc = 0; tc < 4; ++tc) {
            bloA[tc] = *(const bf16x8*)(blbase + (ktA * 4 + tc) * 512);
            bloB[tc] = *(const bf16x8*)(blbase + (ktB * 4 + tc) * 512);
            bloC[tc] = *(const bf16x8*)(blbase + (ktC * 4 + tc) * 512);
        }
    }

    // ---- epilogue-role constants: one (row, unit) cell per thread ----------
    const int erow = tid >> 4;          // 0..31
    const int eun = tid & 15;           // 0..15
    float br[4];
    #pragma unroll
    for (int g = 0; g < 4; ++g) br[g] = bias[g * HIDDEN + u0 + eun];
    const size_t oidx = (size_t)(m0 + erow) * HIDDEN + u0 + eun;
    float c = c_st[oidx];               // zeroed by memset at call start

    int* const cnt_p  = bar + mb * 64;
    int* const flag_p = bar + mb * 64 + 32;

    __syncthreads();   // LDS Bhi ready

    #pragma unroll 1
    for (int s = 0; s < NSTEP; ++s) {
        const int t = base + s;
        const unsigned* hin = (t & 1) ? hp1 : hp0;
        unsigned* hout = (t & 1) ? hp0 : hp1;

        f32x4 acc[2][4];
        #pragma unroll
        for (int mg = 0; mg < 2; ++mg)
            #pragma unroll
            for (int tc = 0; tc < 4; ++tc)
                acc[mg][tc] = (f32x4){0.f, 0.f, 0.f, 0.f};

        // ---- x tile (independent of h) before the gate ---------------------
        if (w < 5) {
            bf16x8 ahi[2], alo[2];
            #pragma unroll
            for (int mg = 0; mg < 2; ++mg) {
                const int b = m0 + mg * 16 + nn;
                const float* src = (ktA < 4)
                    ? feat + ((size_t)b * TSTEPS + t) * FEATD + ktA * 32 + kg * 8
                    : act  + ((size_t)b * TSTEPS + t) * ACTD  + kg * 8;
                const float4 v0 = *(const float4*)src;
                const float4 v1 = *(const float4*)(src + 4);
                const float vv[8] = {v0.x, v0.y, v0.z, v0.w, v1.x, v1.y, v1.z, v1.w};
                #pragma unroll
                for (int j = 0; j < 8; ++j) {
                    const unsigned short h = f2bf(vv[j]);
                    ahi[mg][j] = (short)h;
                    alo[mg][j] = (short)f2bf(vv[j] - bf2f(h));
                }
            }
            #pragma unroll
            for (int tc = 0; tc < 4; ++tc) {
                const bf16x8 bhv = *(const bf16x8*)(lds_bhi + (ktA * 4 + tc) * 512 + lane * 8);
                #pragma unroll
                for (int mg = 0; mg < 2; ++mg) {
                    acc[mg][tc] = __builtin_amdgcn_mfma_f32_16x16x32_bf16(ahi[mg], bhv, acc[mg][tc], 0, 0, 0);
                    acc[mg][tc] = __builtin_amdgcn_mfma_f32_16x16x32_bf16(alo[mg], bhv, acc[mg][tc], 0, 0, 0);
                    acc[mg][tc] = __builtin_amdgcn_mfma_f32_16x16x32_bf16(ahi[mg], bloA[tc], acc[mg][tc], 0, 0, 0);
                }
            }
        }

        // ---- gate: wave 0 polls the monotonic flag (relaxed, no fences) ----
        if (w == 0 && t > 0) {
            while (__hip_atomic_load(flag_p, __ATOMIC_RELAXED,
                                     __HIP_MEMORY_SCOPE_AGENT) < t)
                __builtin_amdgcn_s_sleep(2);
        }
        __syncthreads();                 // gate + protects zbuf from prev step
        asm volatile("" ::: "memory");

        // ---- h tiles: coherent packed loads + unpack + MFMA ----------------
        {
            const int hkB = ktB * 32 - DIMD + kg * 8;
            const int hkC = ktC * 32 - DIMD + kg * 8;
            bf16x8 hBhi[2], hBlo[2], hChi[2], hClo[2];
            #pragma unroll
            for (int mg = 0; mg < 2; ++mg) {
                const int b = m0 + mg * 16 + nn;
                h_frag(hin + (size_t)b * HIDDEN + hkB, hBhi[mg], hBlo[mg]);
                h_frag(hin + (size_t)b * HIDDEN + hkC, hChi[mg], hClo[mg]);
            }
            #pragma unroll
            for (int tc = 0; tc < 4; ++tc) {
                const bf16x8 bhv = *(const bf16x8*)(lds_bhi + (ktB * 4 + tc) * 512 + lane * 8);
                #pragma unroll
                for (int mg = 0; mg < 2; ++mg) {
                    acc[mg][tc] = __builtin_amdgcn_mfma_f32_16x16x32_bf16(hBhi[mg], bhv, acc[mg][tc], 0, 0, 0);
                    acc[mg][tc] = __builtin_amdgcn_mfma_f32_16x16x32_bf16(hBlo[mg], bhv, acc[mg][tc], 0, 0, 0);
                    acc[mg][tc] = __builtin_amdgcn_mfma_f32_16x16x32_bf16(hBhi[mg], bloB[tc], acc[mg][tc], 0, 0, 0);
                }
            }
            #pragma unroll
            for (int tc = 0; tc < 4; ++tc) {
                const bf16x8 bhv = *(const bf16x8*)(lds_bhi + (ktC * 4 + tc) * 512 + lane * 8);
                #pragma unroll
                for (int mg = 0; mg < 2; ++mg) {
                    acc[mg][tc] = __builtin_amdgcn_mfma_f32_16x16x32_bf16(hChi[mg], bhv, acc[mg][tc], 0, 0, 0);
                    acc[mg][tc] = __builtin_amdgcn_mfma_f32_16x16x32_bf16(hClo[mg], bhv, acc[mg][tc], 0, 0, 0);
                    acc[mg][tc] = __builtin_amdgcn_mfma_f32_16x16x32_bf16(hChi[mg], bloC[tc], acc[mg][tc], 0, 0, 0);
                }
            }
        }

        // ---- partials -> LDS ------------------------------------------------
        #pragma unroll
        for (int mg = 0; mg < 2; ++mg)
            #pragma unroll
            for (int tc = 0; tc < 4; ++tc)
                #pragma unroll
                for (int r = 0; r < 4; ++r)
                    zbuf[w * SW + (mg * 16 + kg * 4 + r) * SB + tc * 16 + nn] = acc[mg][tc][r];
        __syncthreads();

        // ---- reduce + gates; c in regs; coherent packed h store ------------
        float zg[4];
        #pragma unroll
        for (int g = 0; g < 4; ++g) {
            float ssum = 0.f;
            #pragma unroll
            for (int ww = 0; ww < NWAVES; ++ww)
                ssum += zbuf[ww * SW + erow * SB + g * 16 + eun];
            zg[g] = ssum;
        }
        const float ig = fast_sigmoid(zg[0] + br[0]);
        const float fg = fast_sigmoid(zg[1] + br[1]);
        const float gg = fast_tanh   (zg[2] + br[2]);
        const float og = fast_sigmoid(zg[3] + br[3]);
        c = fg * c + ig * gg;
        const float hv = og * fast_tanh(c);
        const unsigned short hh = f2bf(hv);
        const unsigned short hl = f2bf(hv - bf2f(hh));
        h_store(hout + oidx, (unsigned)hh | ((unsigned)hl << 16));
        if (t == TSTEPS - 1) out[oidx] = hv;

        // ---- arrive: drain own stores, one relaxed RMW per block -----------
        asm volatile("s_waitcnt vmcnt(0)" ::: "memory");
        __syncthreads();
        if (tid == 0) {
            const int old = __hip_atomic_fetch_add(cnt_p, 1, __ATOMIC_RELAXED,
                                                   __HIP_MEMORY_SCOPE_AGENT);
            if (old == NGROUPS * (t + 1) - 1)
                __hip_atomic_store(flag_p, t + 1, __ATOMIC_RELAXED,
                                   __HIP_MEMORY_SCOPE_AGENT);
        }
    }

    c_st[oidx] = c;   // plain store; next launch reads across kernel boundary
}

extern "C" void kernel_launch(void* const* d_in, const int* in_sizes, int n_in,
                              void* d_out, int out_size, void* d_ws, size_t ws_size,
                              hipStream_t stream) {
    const float* features = (const float*)d_in[0];
    const float* actions  = (const float*)d_in[1];
    const float* W        = (const float*)d_in[2];
    const float* U        = (const float*)d_in[3];
    const float* bias     = (const float*)d_in[4];
    float* out = (float*)d_out;

    const size_t HB = (size_t)BATCH * HIDDEN;          // 131072 cells
    unsigned* hp0 = (unsigned*)d_ws;                   // packed h (hi|lo)
    unsigned* hp1 = hp0 + HB;
    float* c_st = (float*)(hp1 + HB);
    int* bar = (int*)(c_st + HB);                      // 8 groups x 64 ints
    unsigned short* Bhi = (unsigned short*)((char*)bar + 2048);
    unsigned short* Blo = Bhi + (size_t)NFRAGS * 512;

    // zero hp0/hp1 (1 MB), c (512 KB), barrier state (2 KB)
    hipMemsetAsync(d_ws, 0, HB * 4 * 3 + 2048, stream);
    pack_weights<<<(NFRAGS * 64 + 255) / 256, 256, 0, stream>>>(W, U, Bhi, Blo);

    for (int i = 0; i < TSTEPS / NSTEP; ++i) {
        int base = i * NSTEP;
        void* args[] = { (void*)&features, (void*)&actions, (void*)&Bhi,
                         (void*)&Blo, (void*)&bias, (void*)&hp0, (void*)&hp1,
                         (void*)&c_st, (void*)&out, (void*)&bar, (void*)&base };
        hipLaunchCooperativeKernel((const void*)lstm_multi,
                                   dim3(NGROUPS, BATCH / 32), dim3(512),
                                   args, 0, stream);
    }
}

// Round 9
// 5474.984 us; speedup vs baseline: 1.2853x; 1.2853x over previous
//
#include <hip/hip_runtime.h>
#include <math.h>

// LSTM encode, round 9: in-kernel sync with RMW-free barrier.
// 4 cooperative launches x 128 timesteps. Cross-block h via device-coherent
// (relaxed AGENT atomic) packed u32 loads/stores -- no fences, no cache
// invalidation. Per-step sync: each block STOREs step# to its OWN 64B-padded
// flag slot (32 parallel stores, no same-line RMW serialization); wave 0
// polls all 32 slots with one vector load per iteration.
// Bhi in LDS (staged once/launch), Blo in regs, c in regs, bf16x3 MFMA.

#define HIDDEN 512
#define TSTEPS 512
#define BATCH 256
#define FEATD 128
#define ACTD 32
#define DIMD 160
#define GATES 2048
#define NKT 21
#define NGROUPS 32
#define NFRAGS (NGROUPS * NKT * 4)   // 2688

#define NSTEP 128             // timesteps per launch -> 4 launches
#define NWAVES 8
#define SB 66                 // zbuf stride per b-row (f32)
#define SW (32 * SB)
#define FLAG_STRIDE 16        // dwords: one 64B cacheline per flag slot

typedef short bf16x8 __attribute__((ext_vector_type(8)));
typedef float f32x4 __attribute__((ext_vector_type(4)));

__device__ __forceinline__ unsigned short f2bf(float v) {
    union { float f; unsigned u; } c; c.f = v;
    unsigned r = c.u + 0x7fffu + ((c.u >> 16) & 1u);   // RNE
    return (unsigned short)(r >> 16);
}
__device__ __forceinline__ float bf2f(unsigned short s) {
    union { unsigned u; float f; } c; c.u = ((unsigned)s) << 16; return c.f;
}
__device__ __forceinline__ float fast_sigmoid(float x) {
    return 1.0f / (1.0f + __expf(-x));
}
__device__ __forceinline__ float fast_tanh(float x) {
    return 1.0f - 2.0f / (__expf(2.0f * x) + 1.0f);
}

// ---- pack [W;U] (672 x 2048 fp32) into B-fragment-ordered hi/lo bf16 -------
__global__ __launch_bounds__(256)
void pack_weights(const float* __restrict__ W, const float* __restrict__ U,
                  unsigned short* __restrict__ Bhi, unsigned short* __restrict__ Blo)
{
    const int idx = blockIdx.x * 256 + threadIdx.x;
    if (idx >= NFRAGS * 64) return;
    const int lane = idx & 63;
    const int f = idx >> 6;
    const int tc = f & 3;
    const int kt = (f >> 2) % NKT;
    const int ng = (f >> 2) / NKT;
    const int col = tc * HIDDEN + ng * 16 + (lane & 15);
    const int kbase = kt * 32 + (lane >> 4) * 8;
    #pragma unroll
    for (int j = 0; j < 8; ++j) {
        const int k = kbase + j;
        const float v = (k < DIMD) ? W[(size_t)k * GATES + col]
                                   : U[(size_t)(k - DIMD) * GATES + col];
        const unsigned short hi = f2bf(v);
        Bhi[(size_t)idx * 8 + j] = hi;
        Blo[(size_t)idx * 8 + j] = f2bf(v - bf2f(hi));
    }
}

// coherent (device-scope) u32 load/store
__device__ __forceinline__ unsigned h_load(const unsigned* p) {
    return __hip_atomic_load(p, __ATOMIC_RELAXED, __HIP_MEMORY_SCOPE_AGENT);
}
__device__ __forceinline__ void h_store(unsigned* p, unsigned v) {
    __hip_atomic_store(p, v, __ATOMIC_RELAXED, __HIP_MEMORY_SCOPE_AGENT);
}

// load 8 packed cells -> hi/lo bf16x8 fragments
__device__ __forceinline__ void h_frag(const unsigned* base, bf16x8& hi, bf16x8& lo) {
    unsigned v[8];
    #pragma unroll
    for (int j = 0; j < 8; ++j) v[j] = h_load(base + j);
    union { bf16x8 s; unsigned u[4]; } PH, PL;
    #pragma unroll
    for (int j = 0; j < 4; ++j) {
        const unsigned a = v[2 * j], b = v[2 * j + 1];
        PH.u[j] = (a & 0xffffu) | (b << 16);
        PL.u[j] = (a >> 16) | (b & 0xffff0000u);
    }
    hi = PH.s; lo = PL.s;
}

__global__ __launch_bounds__(512, 1)
void lstm_multi(const float* __restrict__ feat, const float* __restrict__ act,
                const unsigned short* __restrict__ Bhi,
                const unsigned short* __restrict__ Blo,
                const float* __restrict__ bias,
                unsigned* __restrict__ hp0, unsigned* __restrict__ hp1,
                float* __restrict__ c_st, float* __restrict__ out,
                int* __restrict__ bar, int base)
{
    __shared__ unsigned short lds_bhi[84 * 512];   // 86016 B
    __shared__ float zbuf[NWAVES * SW];            // 67584 B (total 153600)

    const int tid = threadIdx.x;
    const int lane = tid & 63;
    const int w = tid >> 6;
    const int ng = blockIdx.x;
    const int mb = blockIdx.y;
    const int m0 = mb * 32;
    const int u0 = ng * 16;
    const int kg = lane >> 4;
    const int nn = lane & 15;

    // ---- stage my Bhi slab into LDS (amortized over NSTEP steps) -----------
    {
        const uint4* src = (const uint4*)(Bhi + (size_t)ng * 84 * 512);
        uint4* dst = (uint4*)lds_bhi;
        for (int i = tid; i < 84 * 512 / 8; i += 512) dst[i] = src[i];
    }

    // ---- per-wave K assignment; Blo slices in registers --------------------
    const int ktA = (w < 5) ? w : 5;    // x tile for w<5 (dummy otherwise)
    const int ktB = 5 + 2 * w;          // h tiles {5,6}..{19,20}
    const int ktC = 6 + 2 * w;
    bf16x8 bloA[4], bloB[4], bloC[4];
    {
        const unsigned short* blbase = Blo + (size_t)ng * NKT * 2048 + (size_t)lane * 8;
        #pragma unroll
        for (int tc = 0; tc < 4; ++tc) {
            bloA[tc] = *(const bf16x8*)(blbase + (ktA * 4 + tc) * 512);
            bloB[tc] = *(const bf16x8*)(blbase + (ktB * 4 + tc) * 512);
            bloC[tc] = *(const bf16x8*)(blbase + (ktC * 4 + tc) * 512);
        }
    }

    // ---- epilogue-role constants: one (row, unit) cell per thread ----------
    const int erow = tid >> 4;          // 0..31
    const int eun = tid & 15;           // 0..15
    float br[4];
    #pragma unroll
    for (int g = 0; g < 4; ++g) br[g] = bias[g * HIDDEN + u0 + eun];
    const size_t oidx = (size_t)(m0 + erow) * HIDDEN + u0 + eun;
    float c = c_st[oidx];

    int* const myflag = bar + (mb * 32 + ng) * FLAG_STRIDE;
    int* const pollbase = bar + (mb * 32) * FLAG_STRIDE;

    __syncthreads();   // LDS Bhi ready

    #pragma unroll 1
    for (int s = 0; s < NSTEP; ++s) {
        const int t = base + s;
        const unsigned* hin = (t & 1) ? hp1 : hp0;
        unsigned* hout = (t & 1) ? hp0 : hp1;

        f32x4 acc[2][4];
        #pragma unroll
        for (int mg = 0; mg < 2; ++mg)
            #pragma unroll
            for (int tc = 0; tc < 4; ++tc)
                acc[mg][tc] = (f32x4){0.f, 0.f, 0.f, 0.f};

        // ---- x tile (independent of h) before the gate ---------------------
        if (w < 5) {
            bf16x8 ahi[2], alo[2];
            #pragma unroll
            for (int mg = 0; mg < 2; ++mg) {
                const int b = m0 + mg * 16 + nn;
                const float* src = (ktA < 4)
                    ? feat + ((size_t)b * TSTEPS + t) * FEATD + ktA * 32 + kg * 8
                    : act  + ((size_t)b * TSTEPS + t) * ACTD  + kg * 8;
                const float4 v0 = *(const float4*)src;
                const float4 v1 = *(const float4*)(src + 4);
                const float vv[8] = {v0.x, v0.y, v0.z, v0.w, v1.x, v1.y, v1.z, v1.w};
                #pragma unroll
                for (int j = 0; j < 8; ++j) {
                    const unsigned short h = f2bf(vv[j]);
                    ahi[mg][j] = (short)h;
                    alo[mg][j] = (short)f2bf(vv[j] - bf2f(h));
                }
            }
            #pragma unroll
            for (int tc = 0; tc < 4; ++tc) {
                const bf16x8 bhv = *(const bf16x8*)(lds_bhi + (ktA * 4 + tc) * 512 + lane * 8);
                #pragma unroll
                for (int mg = 0; mg < 2; ++mg) {
                    acc[mg][tc] = __builtin_amdgcn_mfma_f32_16x16x32_bf16(ahi[mg], bhv, acc[mg][tc], 0, 0, 0);
                    acc[mg][tc] = __builtin_amdgcn_mfma_f32_16x16x32_bf16(alo[mg], bhv, acc[mg][tc], 0, 0, 0);
                    acc[mg][tc] = __builtin_amdgcn_mfma_f32_16x16x32_bf16(ahi[mg], bloA[tc], acc[mg][tc], 0, 0, 0);
                }
            }
        }

        // ---- gate: wave 0 polls all 32 per-block flags (parallel loads) ----
        if (w == 0 && t > 0) {
            bool done;
            do {
                const int v = (lane < 32)
                    ? __hip_atomic_load(pollbase + lane * FLAG_STRIDE,
                                        __ATOMIC_RELAXED, __HIP_MEMORY_SCOPE_AGENT)
                    : t;
                done = __all(v >= t);
                if (!done) __builtin_amdgcn_s_sleep(1);
            } while (!done);
        }
        __syncthreads();                 // gate + protects zbuf from prev step
        asm volatile("" ::: "memory");

        // ---- h tiles: coherent packed loads + unpack + MFMA ----------------
        {
            const int hkB = ktB * 32 - DIMD + kg * 8;
            const int hkC = ktC * 32 - DIMD + kg * 8;
            bf16x8 hBhi[2], hBlo[2], hChi[2], hClo[2];
            #pragma unroll
            for (int mg = 0; mg < 2; ++mg) {
                const int b = m0 + mg * 16 + nn;
                h_frag(hin + (size_t)b * HIDDEN + hkB, hBhi[mg], hBlo[mg]);
                h_frag(hin + (size_t)b * HIDDEN + hkC, hChi[mg], hClo[mg]);
            }
            #pragma unroll
            for (int tc = 0; tc < 4; ++tc) {
                const bf16x8 bhv = *(const bf16x8*)(lds_bhi + (ktB * 4 + tc) * 512 + lane * 8);
                #pragma unroll
                for (int mg = 0; mg < 2; ++mg) {
                    acc[mg][tc] = __builtin_amdgcn_mfma_f32_16x16x32_bf16(hBhi[mg], bhv, acc[mg][tc], 0, 0, 0);
                    acc[mg][tc] = __builtin_amdgcn_mfma_f32_16x16x32_bf16(hBlo[mg], bhv, acc[mg][tc], 0, 0, 0);
                    acc[mg][tc] = __builtin_amdgcn_mfma_f32_16x16x32_bf16(hBhi[mg], bloB[tc], acc[mg][tc], 0, 0, 0);
                }
            }
            #pragma unroll
            for (int tc = 0; tc < 4; ++tc) {
                const bf16x8 bhv = *(const bf16x8*)(lds_bhi + (ktC * 4 + tc) * 512 + lane * 8);
                #pragma unroll
                for (int mg = 0; mg < 2; ++mg) {
                    acc[mg][tc] = __builtin_amdgcn_mfma_f32_16x16x32_bf16(hChi[mg], bhv, acc[mg][tc], 0, 0, 0);
                    acc[mg][tc] = __builtin_amdgcn_mfma_f32_16x16x32_bf16(hClo[mg], bhv, acc[mg][tc], 0, 0, 0);
                    acc[mg][tc] = __builtin_amdgcn_mfma_f32_16x16x32_bf16(hChi[mg], bloC[tc], acc[mg][tc], 0, 0, 0);
                }
            }
        }

        // ---- partials -> LDS ------------------------------------------------
        #pragma unroll
        for (int mg = 0; mg < 2; ++mg)
            #pragma unroll
            for (int tc = 0; tc < 4; ++tc)
                #pragma unroll
                for (int r = 0; r < 4; ++r)
                    zbuf[w * SW + (mg * 16 + kg * 4 + r) * SB + tc * 16 + nn] = acc[mg][tc][r];
        __syncthreads();

        // ---- reduce + gates; c in regs; coherent packed h store ------------
        float zg[4];
        #pragma unroll
        for (int g = 0; g < 4; ++g) {
            float ssum = 0.f;
            #pragma unroll
            for (int ww = 0; ww < NWAVES; ++ww)
                ssum += zbuf[ww * SW + erow * SB + g * 16 + eun];
            zg[g] = ssum;
        }
        const float ig = fast_sigmoid(zg[0] + br[0]);
        const float fg = fast_sigmoid(zg[1] + br[1]);
        const float gg = fast_tanh   (zg[2] + br[2]);
        const float og = fast_sigmoid(zg[3] + br[3]);
        c = fg * c + ig * gg;
        const float hv = og * fast_tanh(c);
        const unsigned short hh = f2bf(hv);
        const unsigned short hl = f2bf(hv - bf2f(hh));
        h_store(hout + oidx, (unsigned)hh | ((unsigned)hl << 16));
        if (t == TSTEPS - 1) out[oidx] = hv;

        // ---- arrive: drain stores, ONE plain flag store to own slot --------
        asm volatile("s_waitcnt vmcnt(0)" ::: "memory");
        __syncthreads();
        if (tid == 0)
            __hip_atomic_store(myflag, t + 1, __ATOMIC_RELAXED,
                               __HIP_MEMORY_SCOPE_AGENT);
    }

    c_st[oidx] = c;   // next launch reads across kernel boundary
}

extern "C" void kernel_launch(void* const* d_in, const int* in_sizes, int n_in,
                              void* d_out, int out_size, void* d_ws, size_t ws_size,
                              hipStream_t stream) {
    const float* features = (const float*)d_in[0];
    const float* actions  = (const float*)d_in[1];
    const float* W        = (const float*)d_in[2];
    const float* U        = (const float*)d_in[3];
    const float* bias     = (const float*)d_in[4];
    float* out = (float*)d_out;

    const size_t HB = (size_t)BATCH * HIDDEN;          // 131072 cells
    unsigned* hp0 = (unsigned*)d_ws;                   // packed h (hi|lo)
    unsigned* hp1 = hp0 + HB;
    float* c_st = (float*)(hp1 + HB);
    int* bar = (int*)(c_st + HB);                      // 256 slots x 64B = 16 KB
    unsigned short* Bhi = (unsigned short*)((char*)bar + 256 * FLAG_STRIDE * 4);
    unsigned short* Blo = Bhi + (size_t)NFRAGS * 512;

    // zero hp0/hp1 (1 MB), c (512 KB), flag slots (16 KB)
    hipMemsetAsync(d_ws, 0, HB * 4 * 3 + 256 * FLAG_STRIDE * 4, stream);
    pack_weights<<<(NFRAGS * 64 + 255) / 256, 256, 0, stream>>>(W, U, Bhi, Blo);

    for (int i = 0; i < TSTEPS / NSTEP; ++i) {
        int base = i * NSTEP;
        void* args[] = { (void*)&features, (void*)&actions, (void*)&Bhi,
                         (void*)&Blo, (void*)&bias, (void*)&hp0, (void*)&hp1,
                         (void*)&c_st, (void*)&out, (void*)&bar, (void*)&base };
        hipLaunchCooperativeKernel((const void*)lstm_multi,
                                   dim3(NGROUPS, BATCH / 32), dim3(512),
                                   args, 0, stream);
    }
}

// Round 10
// 2993.486 us; speedup vs baseline: 2.3507x; 1.8290x over previous
//
#include <hip/hip_runtime.h>
#include <math.h>

// LSTM encode, round 10: in-kernel sync + LDS-staged h exchange.
// 4 cooperative launches x 128 timesteps, 256 blocks (1/CU) x 512 threads.
// Fix for r9's 8x L3 overfetch: per step each block stages its 32-row h slice
// (64KB packed u32) into LDS with coalesced coherent global_load_dwordx4
// (sc0 sc1), then reads MFMA fragments from LDS with XOR-swizzled ds_read_b128.
// hbuf aliases zbuf (64/66KB). Barrier: per-block 64B flag slots, relaxed
// stores + parallel poll (r9). Bhi in LDS, Blo/c/bias in regs, bf16x3 MFMA.

#define HIDDEN 512
#define TSTEPS 512
#define BATCH 256
#define FEATD 128
#define ACTD 32
#define DIMD 160
#define GATES 2048
#define NKT 21
#define NGROUPS 32
#define NFRAGS (NGROUPS * NKT * 4)   // 2688

#define NSTEP 128             // timesteps per launch -> 4 launches
#define NWAVES 8
#define SB 66                 // zbuf stride per b-row (f32)
#define SW (32 * SB)
#define FLAG_STRIDE 16        // dwords: one 64B cacheline per flag slot

typedef short bf16x8 __attribute__((ext_vector_type(8)));
typedef float f32x4 __attribute__((ext_vector_type(4)));
typedef unsigned u32x4 __attribute__((ext_vector_type(4)));

__device__ __forceinline__ unsigned short f2bf(float v) {
    union { float f; unsigned u; } c; c.f = v;
    unsigned r = c.u + 0x7fffu + ((c.u >> 16) & 1u);   // RNE
    return (unsigned short)(r >> 16);
}
__device__ __forceinline__ float bf2f(unsigned short s) {
    union { unsigned u; float f; } c; c.u = ((unsigned)s) << 16; return c.f;
}
__device__ __forceinline__ float fast_sigmoid(float x) {
    return 1.0f / (1.0f + __expf(-x));
}
__device__ __forceinline__ float fast_tanh(float x) {
    return 1.0f - 2.0f / (__expf(2.0f * x) + 1.0f);
}

// ---- pack [W;U] (672 x 2048 fp32) into B-fragment-ordered hi/lo bf16 -------
__global__ __launch_bounds__(256)
void pack_weights(const float* __restrict__ W, const float* __restrict__ U,
                  unsigned short* __restrict__ Bhi, unsigned short* __restrict__ Blo)
{
    const int idx = blockIdx.x * 256 + threadIdx.x;
    if (idx >= NFRAGS * 64) return;
    const int lane = idx & 63;
    const int f = idx >> 6;
    const int tc = f & 3;
    const int kt = (f >> 2) % NKT;
    const int ng = (f >> 2) / NKT;
    const int col = tc * HIDDEN + ng * 16 + (lane & 15);
    const int kbase = kt * 32 + (lane >> 4) * 8;
    #pragma unroll
    for (int j = 0; j < 8; ++j) {
        const int k = kbase + j;
        const float v = (k < DIMD) ? W[(size_t)k * GATES + col]
                                   : U[(size_t)(k - DIMD) * GATES + col];
        const unsigned short hi = f2bf(v);
        Bhi[(size_t)idx * 8 + j] = hi;
        Blo[(size_t)idx * 8 + j] = f2bf(v - bf2f(hi));
    }
}

// coherent (device-scope) u32 store of packed h (hi | lo<<16)
__device__ __forceinline__ void h_store(unsigned* p, unsigned v) {
    __hip_atomic_store(p, v, __ATOMIC_RELAXED, __HIP_MEMORY_SCOPE_AGENT);
}

// unpack 8 packed cells (2 x u32x4) -> hi/lo bf16x8 fragments
__device__ __forceinline__ void unpack_frag(u32x4 q0, u32x4 q1,
                                            bf16x8& hi, bf16x8& lo) {
    union { bf16x8 s; unsigned u[4]; } H, L;
    H.u[0] = (q0.x & 0xffffu) | (q0.y << 16);
    L.u[0] = (q0.x >> 16) | (q0.y & 0xffff0000u);
    H.u[1] = (q0.z & 0xffffu) | (q0.w << 16);
    L.u[1] = (q0.z >> 16) | (q0.w & 0xffff0000u);
    H.u[2] = (q1.x & 0xffffu) | (q1.y << 16);
    L.u[2] = (q1.x >> 16) | (q1.y & 0xffff0000u);
    H.u[3] = (q1.z & 0xffffu) | (q1.w << 16);
    L.u[3] = (q1.z >> 16) | (q1.w & 0xffff0000u);
    hi = H.s; lo = L.s;
}

__global__ __launch_bounds__(512, 1)
void lstm_multi(const float* __restrict__ feat, const float* __restrict__ act,
                const unsigned short* __restrict__ Bhi,
                const unsigned short* __restrict__ Blo,
                const float* __restrict__ bias,
                unsigned* __restrict__ hp0, unsigned* __restrict__ hp1,
                float* __restrict__ c_st, float* __restrict__ out,
                int* __restrict__ bar, int base)
{
    __shared__ unsigned short lds_bhi[84 * 512];   // 86016 B
    __shared__ char lds_dyn[NWAVES * SW * 4];      // 67584 B: hbuf (64K) / zbuf
    unsigned* const hbuf = (unsigned*)lds_dyn;     //   aliased; separated by syncs
    float* const zbuf = (float*)lds_dyn;

    const int tid = threadIdx.x;
    const int lane = tid & 63;
    const int w = tid >> 6;
    const int ng = blockIdx.x;
    const int mb = blockIdx.y;
    const int m0 = mb * 32;
    const int u0 = ng * 16;
    const int kg = lane >> 4;
    const int nn = lane & 15;

    // ---- stage my Bhi slab into LDS (amortized over NSTEP steps) -----------
    {
        const uint4* src = (const uint4*)(Bhi + (size_t)ng * 84 * 512);
        uint4* dst = (uint4*)lds_bhi;
        for (int i = tid; i < 84 * 512 / 8; i += 512) dst[i] = src[i];
    }

    // ---- per-wave K assignment; Blo slices in registers --------------------
    const int ktA = (w < 5) ? w : 5;    // x tile for w<5 (dummy otherwise)
    const int ktB = 5 + 2 * w;          // h tiles {5,6}..{19,20}
    const int ktC = 6 + 2 * w;
    bf16x8 bloA[4], bloB[4], bloC[4];
    {
        const unsigned short* blbase = Blo + (size_t)ng * NKT * 2048 + (size_t)lane * 8;
        #pragma unroll
        for (int tc = 0; tc < 4; ++tc) {
            bloA[tc] = *(const bf16x8*)(blbase + (ktA * 4 + tc) * 512);
            bloB[tc] = *(const bf16x8*)(blbase + (ktB * 4 + tc) * 512);
            bloC[tc] = *(const bf16x8*)(blbase + (ktC * 4 + tc) * 512);
        }
    }

    // ---- epilogue-role constants: one (row, unit) cell per thread ----------
    const int erow = tid >> 4;          // 0..31
    const int eun = tid & 15;           // 0..15
    float br[4];
    #pragma unroll
    for (int g = 0; g < 4; ++g) br[g] = bias[g * HIDDEN + u0 + eun];
    const size_t oidx = (size_t)(m0 + erow) * HIDDEN + u0 + eun;
    float c = c_st[oidx];

    int* const myflag = bar + (mb * 32 + ng) * FLAG_STRIDE;
    int* const pollbase = bar + (mb * 32) * FLAG_STRIDE;

    __syncthreads();   // LDS Bhi ready

    #pragma unroll 1
    for (int s = 0; s < NSTEP; ++s) {
        const int t = base + s;
        const unsigned* hin = (t & 1) ? hp1 : hp0;
        unsigned* hout = (t & 1) ? hp0 : hp1;

        f32x4 acc[2][4];
        #pragma unroll
        for (int mg = 0; mg < 2; ++mg)
            #pragma unroll
            for (int tc = 0; tc < 4; ++tc)
                acc[mg][tc] = (f32x4){0.f, 0.f, 0.f, 0.f};

        // ---- x tile (independent of h) before the gate ---------------------
        if (w < 5) {
            bf16x8 ahi[2], alo[2];
            #pragma unroll
            for (int mg = 0; mg < 2; ++mg) {
                const int b = m0 + mg * 16 + nn;
                const float* src = (ktA < 4)
                    ? feat + ((size_t)b * TSTEPS + t) * FEATD + ktA * 32 + kg * 8
                    : act  + ((size_t)b * TSTEPS + t) * ACTD  + kg * 8;
                const float4 v0 = *(const float4*)src;
                const float4 v1 = *(const float4*)(src + 4);
                const float vv[8] = {v0.x, v0.y, v0.z, v0.w, v1.x, v1.y, v1.z, v1.w};
                #pragma unroll
                for (int j = 0; j < 8; ++j) {
                    const unsigned short h = f2bf(vv[j]);
                    ahi[mg][j] = (short)h;
                    alo[mg][j] = (short)f2bf(vv[j] - bf2f(h));
                }
            }
            #pragma unroll
            for (int tc = 0; tc < 4; ++tc) {
                const bf16x8 bhv = *(const bf16x8*)(lds_bhi + (ktA * 4 + tc) * 512 + lane * 8);
                #pragma unroll
                for (int mg = 0; mg < 2; ++mg) {
                    acc[mg][tc] = __builtin_amdgcn_mfma_f32_16x16x32_bf16(ahi[mg], bhv, acc[mg][tc], 0, 0, 0);
                    acc[mg][tc] = __builtin_amdgcn_mfma_f32_16x16x32_bf16(alo[mg], bhv, acc[mg][tc], 0, 0, 0);
                    acc[mg][tc] = __builtin_amdgcn_mfma_f32_16x16x32_bf16(ahi[mg], bloA[tc], acc[mg][tc], 0, 0, 0);
                }
            }
        }

        // ---- gate: wave 0 polls all 32 per-block flags (parallel loads) ----
        if (w == 0 && t > 0) {
            bool done;
            do {
                const int v = (lane < 32)
                    ? __hip_atomic_load(pollbase + lane * FLAG_STRIDE,
                                        __ATOMIC_RELAXED, __HIP_MEMORY_SCOPE_AGENT)
                    : t;
                done = __all(v >= t);
                if (!done) __builtin_amdgcn_s_sleep(1);
            } while (!done);
        }
        __syncthreads();                 // (A) h(t) ready; prev zbuf reads done

        // ---- stage h slice (32 rows x 512 u32 = 64KB) into LDS -------------
        // coalesced coherent 16B loads (sc0 sc1 -> bypass L1/L2, read L3),
        // XOR-swizzled ds_write: byte ^= (row&7)<<4 (kills 2KB-stride conflicts)
        {
            u32x4 hv[8];
            #pragma unroll
            for (int i = 0; i < 8; ++i) {
                const int cch = tid + 512 * i;          // 16B chunk id, 0..4095
                const int row = cch >> 7;
                const int k4 = cch & 127;
                const unsigned* gp = hin + (size_t)(m0 + row) * HIDDEN + k4 * 4;
                asm volatile("global_load_dwordx4 %0, %1, off sc0 sc1"
                             : "=v"(hv[i]) : "v"(gp));
            }
            asm volatile("s_waitcnt vmcnt(0)" ::: "memory");
            #pragma unroll
            for (int i = 0; i < 8; ++i) {
                const int cch = tid + 512 * i;
                const int row = cch >> 7;
                const int k4 = cch & 127;
                const unsigned off = (unsigned)(row * 2048 + k4 * 16)
                                     ^ (unsigned)((row & 7) << 4);
                *(u32x4*)(lds_dyn + off) = hv[i];
            }
        }
        __syncthreads();                 // (B) hbuf complete

        // ---- h tiles: swizzled ds_read_b128 + unpack + MFMA ----------------
        {
            bf16x8 hBhi[2], hBlo[2], hChi[2], hClo[2];
            #pragma unroll
            for (int mg = 0; mg < 2; ++mg) {
                const int r = mg * 16 + nn;
                const unsigned sw = (unsigned)((r & 7) << 4);
                const unsigned baseB = (unsigned)(r * 2048 + (ktB * 32 - DIMD + kg * 8) * 4);
                const unsigned baseC = (unsigned)(r * 2048 + (ktC * 32 - DIMD + kg * 8) * 4);
                const u32x4 qB0 = *(const u32x4*)(lds_dyn + (baseB ^ sw));
                const u32x4 qB1 = *(const u32x4*)(lds_dyn + ((baseB + 16) ^ sw));
                const u32x4 qC0 = *(const u32x4*)(lds_dyn + (baseC ^ sw));
                const u32x4 qC1 = *(const u32x4*)(lds_dyn + ((baseC + 16) ^ sw));
                unpack_frag(qB0, qB1, hBhi[mg], hBlo[mg]);
                unpack_frag(qC0, qC1, hChi[mg], hClo[mg]);
            }
            #pragma unroll
            for (int tc = 0; tc < 4; ++tc) {
                const bf16x8 bhv = *(const bf16x8*)(lds_bhi + (ktB * 4 + tc) * 512 + lane * 8);
                #pragma unroll
                for (int mg = 0; mg < 2; ++mg) {
                    acc[mg][tc] = __builtin_amdgcn_mfma_f32_16x16x32_bf16(hBhi[mg], bhv, acc[mg][tc], 0, 0, 0);
                    acc[mg][tc] = __builtin_amdgcn_mfma_f32_16x16x32_bf16(hBlo[mg], bhv, acc[mg][tc], 0, 0, 0);
                    acc[mg][tc] = __builtin_amdgcn_mfma_f32_16x16x32_bf16(hBhi[mg], bloB[tc], acc[mg][tc], 0, 0, 0);
                }
            }
            #pragma unroll
            for (int tc = 0; tc < 4; ++tc) {
                const bf16x8 bhv = *(const bf16x8*)(lds_bhi + (ktC * 4 + tc) * 512 + lane * 8);
                #pragma unroll
                for (int mg = 0; mg < 2; ++mg) {
                    acc[mg][tc] = __builtin_amdgcn_mfma_f32_16x16x32_bf16(hChi[mg], bhv, acc[mg][tc], 0, 0, 0);
                    acc[mg][tc] = __builtin_amdgcn_mfma_f32_16x16x32_bf16(hClo[mg], bhv, acc[mg][tc], 0, 0, 0);
                    acc[mg][tc] = __builtin_amdgcn_mfma_f32_16x16x32_bf16(hChi[mg], bloC[tc], acc[mg][tc], 0, 0, 0);
                }
            }
        }
        __syncthreads();                 // (C) all hbuf reads done -> zbuf ok

        // ---- partials -> LDS (zbuf aliases hbuf) ---------------------------
        #pragma unroll
        for (int mg = 0; mg < 2; ++mg)
            #pragma unroll
            for (int tc = 0; tc < 4; ++tc)
                #pragma unroll
                for (int r = 0; r < 4; ++r)
                    zbuf[w * SW + (mg * 16 + kg * 4 + r) * SB + tc * 16 + nn] = acc[mg][tc][r];
        __syncthreads();                 // (D)

        // ---- reduce + gates; c in regs; coherent packed h store ------------
        float zg[4];
        #pragma unroll
        for (int g = 0; g < 4; ++g) {
            float ssum = 0.f;
            #pragma unroll
            for (int ww = 0; ww < NWAVES; ++ww)
                ssum += zbuf[ww * SW + erow * SB + g * 16 + eun];
            zg[g] = ssum;
        }
        const float ig = fast_sigmoid(zg[0] + br[0]);
        const float fg = fast_sigmoid(zg[1] + br[1]);
        const float gg = fast_tanh   (zg[2] + br[2]);
        const float og = fast_sigmoid(zg[3] + br[3]);
        c = fg * c + ig * gg;
        const float hv = og * fast_tanh(c);
        const unsigned short hh = f2bf(hv);
        const unsigned short hl = f2bf(hv - bf2f(hh));
        h_store(hout + oidx, (unsigned)hh | ((unsigned)hl << 16));
        if (t == TSTEPS - 1) out[oidx] = hv;

        // ---- arrive: drain stores, ONE flag store to own slot --------------
        asm volatile("s_waitcnt vmcnt(0)" ::: "memory");
        __syncthreads();                 // (E)
        if (tid == 0)
            __hip_atomic_store(myflag, t + 1, __ATOMIC_RELAXED,
                               __HIP_MEMORY_SCOPE_AGENT);
    }

    c_st[oidx] = c;   // next launch reads across kernel boundary
}

extern "C" void kernel_launch(void* const* d_in, const int* in_sizes, int n_in,
                              void* d_out, int out_size, void* d_ws, size_t ws_size,
                              hipStream_t stream) {
    const float* features = (const float*)d_in[0];
    const float* actions  = (const float*)d_in[1];
    const float* W        = (const float*)d_in[2];
    const float* U        = (const float*)d_in[3];
    const float* bias     = (const float*)d_in[4];
    float* out = (float*)d_out;

    const size_t HB = (size_t)BATCH * HIDDEN;          // 131072 cells
    unsigned* hp0 = (unsigned*)d_ws;                   // packed h (hi|lo)
    unsigned* hp1 = hp0 + HB;
    float* c_st = (float*)(hp1 + HB);
    int* bar = (int*)(c_st + HB);                      // 256 slots x 64B = 16 KB
    unsigned short* Bhi = (unsigned short*)((char*)bar + 256 * FLAG_STRIDE * 4);
    unsigned short* Blo = Bhi + (size_t)NFRAGS * 512;

    // zero hp0/hp1 (1 MB), c (512 KB), flag slots (16 KB)
    hipMemsetAsync(d_ws, 0, HB * 4 * 3 + 256 * FLAG_STRIDE * 4, stream);
    pack_weights<<<(NFRAGS * 64 + 255) / 256, 256, 0, stream>>>(W, U, Bhi, Blo);

    for (int i = 0; i < TSTEPS / NSTEP; ++i) {
        int base = i * NSTEP;
        void* args[] = { (void*)&features, (void*)&actions, (void*)&Bhi,
                         (void*)&Blo, (void*)&bias, (void*)&hp0, (void*)&hp1,
                         (void*)&c_st, (void*)&out, (void*)&bar, (void*)&base };
        hipLaunchCooperativeKernel((const void*)lstm_multi,
                                   dim3(NGROUPS, BATCH / 32), dim3(512),
                                   args, 0, stream);
    }
}